// Round 1
// baseline (403.085 us; speedup 1.0000x reference)
//
#include <hip/hip_runtime.h>
#include <hip/hip_bf16.h>
#include <math.h>

#define NB 8
#define INCH 512
#define OUTCH 256
#define SP 4096          // 64*64 spatial
#define LAT 512
#define NTAP 9
#define MDIM (NTAP*OUTCH)   // 2304

#define INV_SQRT_LAT 0.044194173824159216f   // 1/sqrt(512)
#define WSCALE 0.014731391274719738f         // 1/sqrt(512*9)

typedef __bf16 bf16x8 __attribute__((ext_vector_type(8)));
typedef float  f32x4  __attribute__((ext_vector_type(4)));

__device__ __forceinline__ unsigned short f2bf(float f) {
  unsigned u = __float_as_uint(f);
  u += 0x7fffu + ((u >> 16) & 1u);       // round-to-nearest-even
  return (unsigned short)(u >> 16);
}
__device__ __forceinline__ float bf2f(unsigned short v) {
  return __uint_as_float((unsigned)v << 16);
}

// ---------------- stage 0a+0b fused: style GEMV (blocks 0..15) + weight prep (blocks 16..527)
__global__ void prep_k(const float* __restrict__ w, const float* __restrict__ aff,
                       const float* __restrict__ bias, float* __restrict__ style,
                       const float* __restrict__ cw, float* __restrict__ S,
                       unsigned short* __restrict__ w9) {
  if (blockIdx.x < 16) {
    int gid = blockIdx.x * 256 + threadIdx.x;       // 4096
    int b = gid >> 9, i = gid & 511;
    const float4* wv = (const float4*)(w + (size_t)b * LAT);
    const float4* av = (const float4*)(aff + (size_t)i * LAT);
    float s = 0.f;
#pragma unroll 4
    for (int l = 0; l < LAT / 4; ++l) {
      float4 a = av[l], ww = wv[l];
      s += a.x * ww.x + a.y * ww.y + a.z * ww.z + a.w * ww.w;
    }
    style[gid] = s * INV_SQRT_LAT + bias[i];
  } else {
    int gid = (blockIdx.x - 16) * 256 + threadIdx.x;  // 131072 = 256*512
    int o = gid >> 9, i = gid & 511;
    const float* p = cw + (size_t)gid * 9;            // layout (o,i,3,3)
    float ss = 0.f, v[9];
#pragma unroll
    for (int t = 0; t < 9; ++t) { v[t] = p[t]; ss += v[t] * v[t]; }
    S[gid] = ss * (WSCALE * WSCALE);
#pragma unroll
    for (int t = 0; t < 9; ++t)
      w9[((size_t)(t * OUTCH + o)) * INCH + i] = f2bf(v[t] * WSCALE);
  }
}

// ---------------- stage 0c: demod[b,o] = rsqrt(sum_i style^2 * S + 1e-8)
__global__ void demod_k(const float* __restrict__ style, const float* __restrict__ S,
                        float* __restrict__ dmod) {
  int gid = blockIdx.x * 256 + threadIdx.x;       // 2048
  int b = gid >> 8, o = gid & 255;
  const float4* sv = (const float4*)(style + (size_t)b * INCH);
  const float4* Sv = (const float4*)(S + (size_t)o * INCH);
  float acc = 0.f;
#pragma unroll 4
  for (int l = 0; l < INCH / 4; ++l) {
    float4 st = sv[l], s2 = Sv[l];
    acc += st.x * st.x * s2.x + st.y * st.y * s2.y + st.z * st.z * s2.z + st.w * st.w * s2.w;
  }
  dmod[gid] = 1.0f / sqrtf(acc + 1e-8f);
}

// ---------------- stage 0d: xmt[b][s][i] = bf16(x[b][i][s] * style[b][i])   (transpose)
__global__ void modx_k(const float* __restrict__ x, const float* __restrict__ style,
                       unsigned short* __restrict__ xmt) {
  __shared__ float tile[32][33];
  int b = blockIdx.z;
  int s0 = blockIdx.x * 32;
  int i0 = blockIdx.y * 32;
  int c = threadIdx.x & 31, r = threadIdx.x >> 5;   // 32 x 8
#pragma unroll
  for (int p = 0; p < 4; ++p) {
    int ii = r + p * 8;
    tile[ii][c] = x[((size_t)(b * INCH + i0 + ii)) * SP + s0 + c] * style[b * INCH + i0 + ii];
  }
  __syncthreads();
#pragma unroll
  for (int p = 0; p < 4; ++p) {
    int ss = r + p * 8;
    xmt[((size_t)(b * SP + s0 + ss)) * INCH + i0 + c] = f2bf(tile[c][ss]);
  }
}

// ---------------- stage 1: T[m, n] = sum_k A[m,k] * B[n,k]
// 256x256 tile, BK=64, 512 thr (8 waves 2Mx4N), 128 KiB LDS double-buffer.
// 4 phases per K-tile: {ds_read subtile || stage -> s_barrier -> 16 MFMA (setprio) -> s_barrier}.
// Tile t+1's 8 global_load_lds issued at phase 1 of tile t; per-wave vmcnt(0) only at
// tile boundary (loads have ~4 phases of MFMA cover). Raw s_barrier (no compiler drain).
__global__ __launch_bounds__(512, 2)
void gemm_k(const unsigned short* __restrict__ A,   // MDIM x INCH
            const unsigned short* __restrict__ Bm,  // NB x SP x INCH
            unsigned short* __restrict__ C) {       // NB x MDIM x SP (bf16)
  __shared__ __align__(16) unsigned short lds[65536];  // 128 KiB: A dbuf @0, B dbuf @32768
  Bm += (size_t)blockIdx.z * SP * INCH;
  C  += (size_t)blockIdx.z * MDIM * SP;
  const int tid  = threadIdx.x;
  const int lane = tid & 63;
  const int wid  = tid >> 6;          // 0..7
  const int wr   = wid >> 2;          // 0..1 -> 128-row m-half
  const int wc   = wid & 3;           // 0..3 -> 64-col n-quarter
  const int m0 = blockIdx.y * 256;
  const int n0 = blockIdx.x * 256;
  const int r16  = lane & 15;
  const int quad = lane >> 4;
  const int xorv = r16 & 7;
  const int ch0 = ((0 + quad) ^ xorv) * 8;   // k-chunk for kk=0 (swizzled, elems)
  const int ch1 = ((4 + quad) ^ xorv) * 8;   // k-chunk for kk=1
  const int aBase = (wr * 128 + r16) * 64;
  const int bBase = (wc * 64 + r16) * 64;

  // staging addressing: thread -> row tid>>3, LDS chunk tid&7, global chunk pre-swizzled
  const int srow = tid >> 3;                       // 0..63
  const int sgch = ((tid & 7) ^ (srow & 7)) * 8;   // elems
  const int swb  = wid * 512;                      // wave-uniform LDS elem offset (8 rows * 64)

  f32x4 acc[8][4];
#pragma unroll
  for (int i = 0; i < 8; ++i)
#pragma unroll
    for (int j = 0; j < 4; ++j) acc[i][j] = (f32x4){0.f, 0.f, 0.f, 0.f};

#define STAGE_TILE(T) do {                                                          \
    const int _buf = (T) & 1;                                                       \
    const int _k0  = (T) * 64;                                                      \
    unsigned short* _la = &lds[_buf * 16384 + swb];                                 \
    unsigned short* _lb = &lds[32768 + _buf * 16384 + swb];                         \
    const unsigned short* _ga = A  + (size_t)(m0 + srow) * INCH + _k0 + sgch;       \
    const unsigned short* _gb = Bm + (size_t)(n0 + srow) * INCH + _k0 + sgch;       \
    _Pragma("unroll")                                                               \
    for (int _it = 0; _it < 4; ++_it) {                                             \
      __builtin_amdgcn_global_load_lds(                                             \
          (const __attribute__((address_space(1))) void*)(_ga + (size_t)_it * 64 * INCH), \
          (__attribute__((address_space(3))) void*)(_la + _it * 4096), 16, 0, 0);   \
      __builtin_amdgcn_global_load_lds(                                             \
          (const __attribute__((address_space(1))) void*)(_gb + (size_t)_it * 64 * INCH), \
          (__attribute__((address_space(3))) void*)(_lb + _it * 4096), 16, 0, 0);   \
    }                                                                               \
  } while (0)

#define READ_A(MH) do {                                                             \
    _Pragma("unroll")                                                               \
    for (int _i = 0; _i < 4; ++_i) {                                                \
      const int _rb = aBase + ((MH) * 64 + _i * 16) * 64;                           \
      af[0][_i] = *(const bf16x8*)&As_[_rb + ch0];                                  \
      af[1][_i] = *(const bf16x8*)&As_[_rb + ch1];                                  \
    }                                                                               \
  } while (0)

#define READ_B(NH) do {                                                             \
    _Pragma("unroll")                                                               \
    for (int _j = 0; _j < 2; ++_j) {                                                \
      const int _rb = bBase + ((NH) * 32 + _j * 16) * 64;                           \
      bfr[0][_j] = *(const bf16x8*)&Bs_[_rb + ch0];                                 \
      bfr[1][_j] = *(const bf16x8*)&Bs_[_rb + ch1];                                 \
    }                                                                               \
  } while (0)

#define MFMA_Q(MH, NH) do {                                                         \
    __builtin_amdgcn_s_setprio(1);                                                  \
    _Pragma("unroll")                                                               \
    for (int _kk = 0; _kk < 2; ++_kk)                                               \
    _Pragma("unroll")                                                               \
    for (int _i = 0; _i < 4; ++_i)                                                  \
    _Pragma("unroll")                                                               \
    for (int _j = 0; _j < 2; ++_j)                                                  \
      acc[(MH)*4+_i][(NH)*2+_j] = __builtin_amdgcn_mfma_f32_16x16x32_bf16(          \
          af[_kk][_i], bfr[_kk][_j], acc[(MH)*4+_i][(NH)*2+_j], 0, 0, 0);           \
    __builtin_amdgcn_s_setprio(0);                                                  \
  } while (0)

  STAGE_TILE(0);
  STAGE_TILE(1);
  asm volatile("s_waitcnt vmcnt(8)" ::: "memory");   // tile 0 resident; tile 1 stays in flight
  __builtin_amdgcn_sched_barrier(0);
  __builtin_amdgcn_s_barrier();

  for (int t = 0; t < 8; ++t) {
    const unsigned short* As_ = &lds[(t & 1) * 16384];
    const unsigned short* Bs_ = &lds[32768 + (t & 1) * 16384];
    bf16x8 af[2][4], bfr[2][2];
    // phase 1: quadrant (0,0); issue next tile's loads early (buf (t+1)&1 free since t-1 done)
    if (t >= 1 && t <= 6) STAGE_TILE(t + 1);
    READ_A(0); READ_B(0);
    __builtin_amdgcn_s_barrier();
    MFMA_Q(0, 0);
    __builtin_amdgcn_s_barrier();
    // phase 2: quadrant (0,1) -- reuse A-half0
    READ_B(1);
    __builtin_amdgcn_s_barrier();
    MFMA_Q(0, 1);
    __builtin_amdgcn_s_barrier();
    // phase 3: quadrant (1,1) -- reuse B-half1
    READ_A(1);
    __builtin_amdgcn_s_barrier();
    MFMA_Q(1, 1);
    __builtin_amdgcn_s_barrier();
    // phase 4: quadrant (1,0) -- re-read B-half0
    READ_B(0);
    __builtin_amdgcn_s_barrier();
    MFMA_Q(1, 0);
    if (t < 7) {
      asm volatile("s_waitcnt vmcnt(0)" ::: "memory");   // tile t+1 resident (issued 4 phases ago)
      __builtin_amdgcn_sched_barrier(0);
    }
    __builtin_amdgcn_s_barrier();
  }
#undef STAGE_TILE
#undef READ_A
#undef READ_B
#undef MFMA_Q

  // epilogue: restage full 256x256 bf16 tile in LDS (chunk-XOR swizzle), then dwordx4 stores.
  // C/D layout col=lane&15, row=quad*4+reg [m89].
#pragma unroll
  for (int i = 0; i < 8; ++i)
#pragma unroll
    for (int j = 0; j < 4; ++j)
#pragma unroll
      for (int r = 0; r < 4; ++r) {
        int row = wr * 128 + i * 16 + quad * 4 + r;
        int col = wc * 64 + j * 16 + r16;
        int pc  = (col >> 3) ^ (row & 31);
        lds[row * 256 + pc * 8 + (col & 7)] = f2bf(acc[i][j][r]);
      }
  __syncthreads();
#pragma unroll
  for (int rr = 0; rr < 16; ++rr) {
    int row = rr * 16 + (tid >> 5);
    int c   = tid & 31;
    int pc  = c ^ (row & 31);
    uint4 v = *(const uint4*)&lds[row * 256 + pc * 8];
    *(uint4*)&C[(size_t)(m0 + row) * SP + n0 + c * 8] = v;
  }
}

// ---------------- stage 2: separable parity-combine + 4x4 blur + demod
// Block = (strip of 8 Y-rows, o, b). LDS 27.9KB -> 5 blocks/CU.
// TlB (bf16): rows (tap,ry) ry=0..9 (Yg=Y0-1..Y0+8), col 4 == x=0, stride 70.
// V (fp32): [c][10 rows][32 chunks of 4], stride 128 exactly, XOR chunk swizzle
//   p = (l & ~3) | ((l&3) ^ ((l>>3)&3))  -- conflict-free for both writers and readers.
#define STRIP 8
#define TLSTR 70
#define TLROWS 10
__global__ __launch_bounds__(256)
void combine_k(const unsigned short* __restrict__ T, const float* __restrict__ dm,
               float* __restrict__ out) {
  __shared__ __align__(16) unsigned short TlB[9 * TLROWS * TLSTR + 4];  // 12608 B
  __shared__ __align__(16) float V[3 * TLROWS * 128];                   // 15360 B
  T   += (size_t)blockIdx.z * MDIM * SP;
  dm  += (size_t)blockIdx.z * OUTCH;
  out += (size_t)blockIdx.z * OUTCH * 128 * 128;
  const int o  = blockIdx.y;
  const int Y0 = blockIdx.x * STRIP;
  const int tid = threadIdx.x;

  // zero-fill TlB (halo rows/cols must read 0)
  {
    uint4* tz = (uint4*)TlB;
#pragma unroll
    for (int idx = tid; idx < 788; idx += 256) tz[idx] = (uint4){0u, 0u, 0u, 0u};
  }
  __syncthreads();

  // tap load: 9 taps x 10 rows x 64 cols as ushort4 chunks; 1440 ops
  for (int idx = tid; idx < 1440; idx += 256) {
    int tap = idx / 160;
    int rem = idx - tap * 160;
    int ry  = rem >> 4;
    int c16 = rem & 15;
    int Yg = Y0 - 1 + ry;
    if ((unsigned)Yg < 64u) {
      ushort4 v4 = *(const ushort4*)(T + (size_t)(tap * OUTCH + o) * SP + Yg * 64 + c16 * 4);
      unsigned short* dst = &TlB[(tap * TLROWS + ry) * TLSTR + 4 + c16 * 4];
      *(ushort2*)(dst)     = make_ushort2(v4.x, v4.y);
      *(ushort2*)(dst + 2) = make_ushort2(v4.z, v4.w);
    }
  }
  __syncthreads();

  // x-pass: 30 row-tasks (c 0..2, yr 0..9) x 8 x-chunks of 8 -> V
  {
    const int r  = tid >> 3;
    const int xc = tid & 7;
    if (r < 30) {
      const int c  = r / 10;
      const int yr = r - c * 10;
      const int X0 = xc * 8;
      float td[3][12];
#pragma unroll
      for (int d = 0; d < 3; ++d) {
        const unsigned short* src = &TlB[((c * 3 + d) * TLROWS + yr) * TLSTR + 2 + X0];
#pragma unroll
        for (int k = 0; k < 6; ++k) {
          ushort2 u2 = *(const ushort2*)(src + 2 * k);
          td[d][2 * k]     = bf2f(u2.x);
          td[d][2 * k + 1] = bf2f(u2.y);
        }
      }
      float vout[16];
#pragma unroll
      for (int Xl = 0; Xl < 8; ++Xl) {
        float a0 = td[0][Xl + 1], a1 = td[0][Xl + 2], a2 = td[0][Xl + 3];
        float b0 = td[1][Xl + 1], b1 = td[1][Xl + 2], b2 = td[1][Xl + 3];
        float c0 = td[2][Xl + 1], c1 = td[2][Xl + 2], c2 = td[2][Xl + 3];
        vout[2 * Xl]     = b0 + 3.f * c0 + 3.f * a1 + 3.f * b1 + c1 + a2;
        vout[2 * Xl + 1] = c0 + a1 + 3.f * b1 + 3.f * c1 + 3.f * a2 + b2;
      }
      float* vr = &V[(c * TLROWS + yr) * 128];
#pragma unroll
      for (int j = 0; j < 4; ++j) {
        int l = 4 * xc + j;
        int p = (l & ~3) | ((l & 3) ^ ((l >> 3) & 3));
        *(f32x4*)(vr + p * 4) = (f32x4){vout[4 * j], vout[4 * j + 1], vout[4 * j + 2], vout[4 * j + 3]};
      }
    }
  }
  __syncthreads();

  // y-pass: 16 out rows x 32 chunks; thread = (y=tid>>4, chunk tid&15 + 16*xg)
  {
    const int y  = tid >> 4;        // 0..15
    const int py = y & 1;
    const int Yl = y >> 1;          // 0..7
    const float dmv = dm[o] * (1.0f / 16.0f);
    float* orow = out + ((size_t)o * 128 + (Y0 * 2 + y)) * 128;
#pragma unroll
    for (int xg = 0; xg < 2; ++xg) {
      int l = (tid & 15) + 16 * xg;
      int p = (l & ~3) | ((l & 3) ^ ((l >> 3) & 3));
      int off = p * 4;
      f32x4 v00 = *(const f32x4*)&V[((0 * TLROWS) + Yl + 0) * 128 + off];
      f32x4 v01 = *(const f32x4*)&V[((0 * TLROWS) + Yl + 1) * 128 + off];
      f32x4 v02 = *(const f32x4*)&V[((0 * TLROWS) + Yl + 2) * 128 + off];
      f32x4 v10 = *(const f32x4*)&V[((1 * TLROWS) + Yl + 0) * 128 + off];
      f32x4 v11 = *(const f32x4*)&V[((1 * TLROWS) + Yl + 1) * 128 + off];
      f32x4 v12 = *(const f32x4*)&V[((1 * TLROWS) + Yl + 2) * 128 + off];
      f32x4 v20 = *(const f32x4*)&V[((2 * TLROWS) + Yl + 0) * 128 + off];
      f32x4 v21 = *(const f32x4*)&V[((2 * TLROWS) + Yl + 1) * 128 + off];
      f32x4 v22 = *(const f32x4*)&V[((2 * TLROWS) + Yl + 2) * 128 + off];
      f32x4 r;
      if (py == 0)
        r = v10 + 3.f * v20 + 3.f * v01 + 3.f * v11 + v21 + v02;
      else
        r = v20 + v01 + 3.f * v11 + 3.f * v21 + 3.f * v02 + v12;
      r *= dmv;
      *(f32x4*)(orow + l * 4) = r;
    }
  }
}

extern "C" void kernel_launch(void* const* d_in, const int* in_sizes, int n_in,
                              void* d_out, int out_size, void* d_ws, size_t ws_size,
                              hipStream_t stream) {
  const float* x    = (const float*)d_in[0];
  const float* w    = (const float*)d_in[1];
  const float* aff  = (const float*)d_in[2];
  const float* bias = (const float*)d_in[3];
  const float* cw   = (const float*)d_in[4];
  float* out = (float*)d_out;
  char* ws = (char*)d_ws;
  // ws layout: style 16K | S 512K | demod 8K | w9 2.25M | xmt 32M | T(bf16) 151M
  float* style        = (float*)(ws);
  float* S            = (float*)(ws + 16384);
  float* dmod         = (float*)(ws + 540672);
  unsigned short* w9  = (unsigned short*)(ws + 548864);
  unsigned short* xmt = (unsigned short*)(ws + 2908160);
  unsigned short* T   = (unsigned short*)(ws + 36462592);

  hipLaunchKernelGGL(prep_k, dim3(528), dim3(256), 0, stream, w, aff, bias, style, cw, S, w9);
  hipLaunchKernelGGL(demod_k, dim3(8), dim3(256), 0, stream, style, S, dmod);
  hipLaunchKernelGGL(modx_k, dim3(128, 16, 8), dim3(256), 0, stream, x, style, xmt);
  hipLaunchKernelGGL(gemm_k, dim3(16, 9, NB), dim3(512), 0, stream, w9, xmt, T);
  hipLaunchKernelGGL(combine_k, dim3(64 / STRIP, 256, NB), dim3(256), 0, stream, T, dmod, out);
}